// Round 6
// baseline (972.379 us; speedup 1.0000x reference)
//
#include <hip/hip_runtime.h>
#include <math.h>

// ---------------- problem constants ----------------
#define B_ 8192
#define T_ 223
#define D_ 7
#define H_ 128
#define E_ 50
#define O_ 29
#define A_ 9
#define TD_ (T_*D_)     // 1561
#define NB 32           // batch rows per block -> grid 256 = 1 block/CU
#define NTHR 512
#define MB 8            // batch rows per block (head kernel)
#define MS_BG 128       // msum batch groups
#define IMPST 115       // impbuf batch stride (odd-ish: conflict-free)

// ---------------- workspace layout (float offsets) ----------------
#define WS_MINV  0                            // raw msum_t sums, T floats
#define WS_ACC   (WS_MINV + T_)               // [0]=x_loss raw sum, [1]=y_loss raw sum
#define WS_WCATT (WS_ACC + 2)                 // [178][128] transposed W_cat
#define WS_HFIN  (WS_WCATT + 178*H_)          // final h, [B][128] fp32

// ---------------- output layout (floats) ----------------
#define OUT_YH  3
#define OUT_IMP (OUT_YH + B_*O_)              // 237571
#define OUT_LAB (OUT_IMP + B_*T_*D_)          // 13025283

typedef __attribute__((ext_vector_type(8))) short short8;   // 8 bf16 = 4 VGPRs
typedef __attribute__((ext_vector_type(4))) float floatx4;
#define MFMA16(Av,Bv,Cv) __builtin_amdgcn_mfma_f32_16x16x32_bf16((Av),(Bv),(Cv),0,0,0)

// raw barrier: order LDS only; do NOT drain vmcnt (prefetch floats across)
#define BARRIER() do { asm volatile("s_waitcnt lgkmcnt(0)" ::: "memory"); \
                       __builtin_amdgcn_s_barrier(); } while (0)

__device__ __forceinline__ unsigned short f2bf(float f) {   // RNE fp32->bf16
    unsigned int u = __builtin_bit_cast(unsigned int, f);
    return (unsigned short)((u + 0x7FFFu + ((u >> 16) & 1u)) >> 16);
}
__device__ __forceinline__ float bf2f(unsigned short s) {
    unsigned int u = ((unsigned int)s) << 16;
    return __builtin_bit_cast(float, u);
}
__device__ __forceinline__ float rcp_(float x)  { return __builtin_amdgcn_rcpf(x); }
__device__ __forceinline__ float exp2_(float x) { float r; asm("v_exp_f32 %0, %1"  : "=v"(r) : "v"(x)); return r; }
__device__ __forceinline__ float expn2_(float x){ float r; asm("v_exp_f32 %0, -%1" : "=v"(r) : "v"(x)); return r; }

#define L2E   1.44269504088896f
#define TL2E  2.88539008177793f

// ================= prep: W_cat transpose + zero accumulators =================
__global__ void rits_prep(const float* __restrict__ W_cat, float* __restrict__ ws)
{
    int idx = blockIdx.x * 256 + threadIdx.x;
    if (idx < H_*178) {                      // W_cat [128][178] -> [178][128]
        int j = idx / 178, k = idx - j*178;
        ws[WS_WCATT + k*H_ + j] = W_cat[idx];
    }
    if (idx < T_) ws[WS_MINV + idx] = 0.f;
    if (idx < 2) ws[WS_ACC + idx] = 0.f;
}

// ================= per-step mask sums (coalesced, atomic partials) =================
__global__ void rits_msum(const float* __restrict__ masks, float* __restrict__ ws)
{
    const int tc = blockIdx.x % 7;           // t-chunk of 32 steps
    const int bg = blockIdx.x / 7;           // batch group
    const int t0 = tc * 32;
    const int nt = (t0 + 32 <= T_) ? 32 : (T_ - t0);
    const int ncol = nt * D_;                // 224 or 217
    const int tid = threadIdx.x;
    __shared__ float sums[224];
    float s = 0.f;
    if (tid < ncol) {
        const int bpg = B_ / MS_BG;          // 64
        const float* p = masks + (size_t)bg * bpg * TD_ + (size_t)t0 * D_ + tid;
        #pragma unroll 4
        for (int b = 0; b < bpg; ++b) s += p[(size_t)b * TD_];
    }
    if (tid < 224) sums[tid] = (tid < ncol) ? s : 0.f;
    __syncthreads();
    if (tid < 32) {
        float r = 0.f;
        #pragma unroll
        for (int q = 0; q < 7; ++q) r += sums[tid*7 + q];
        if (t0 + tid < T_) atomicAdd(&ws[WS_MINV + t0 + tid], r);
    }
}

// ================= main scan kernel (MFMA) =================
// TWO raw barriers per step (lgkmcnt-only; no vmcnt drain):
//  [S] -> P12: gate-h MFMAs (32) + m/bias MFMAs (8) on all waves, overlapping
//              A3 spread over all 8 waves (28 lanes each): sum 8 xh partials
//              (ds_bpermute shares the 7 per-row values), z_h/alpha/c_c/loss.
//  [C] -> P3:  c_c MFMAs (8) + decay MFMAs (2) + LSTM (log2e-folded exps)
//              + h write + per-wave partial x_h(t+1) (2 MFMAs, K=16) to
//              xh_part.  No wave-7 specialization.
// exp folding: gate rows of W_hh/W_ih/biases pre-scaled by log2e (2*log2e for
// g-gate); W_td_h/b_td_h and W_td_x/b_td_x by log2e -> v_exp_f32 direct.
__global__ __launch_bounds__(NTHR, 2) void rits_main(
    const float* __restrict__ values, const float* __restrict__ masks, const float* __restrict__ deltas,
    const float* __restrict__ W_td_h, const float* __restrict__ b_td_h,
    const float* __restrict__ W_td_x, const float* __restrict__ b_td_x,
    const float* __restrict__ W_hist, const float* __restrict__ b_hist,
    const float* __restrict__ W_feat, const float* __restrict__ b_feat,
    const float* __restrict__ W_comb, const float* __restrict__ b_comb,
    const float* __restrict__ W_ih, const float* __restrict__ W_hh,
    const float* __restrict__ b_ih, const float* __restrict__ b_hh,
    float* __restrict__ ws, float* __restrict__ out)
{
    // hbuf row (bf16, stride 168): 0..127 h, 128..134 c_c, 135..159 zeros
    __shared__ __attribute__((aligned(16))) unsigned short hbuf[NB*168];
    // bbuf row (bf16, stride 32): 0..6 m(t), 7=1.0, 8..14 d(t+1), 15=1.0, 16..31=0
    __shared__ __attribute__((aligned(16))) unsigned short bbuf[NB*32];
    __shared__ __attribute__((aligned(16))) unsigned short zpad[8];   // 16B zeros
    __shared__ float xh_part[8*NB*8];       // [wave][b][i] partial x_h (fp32)
    __shared__ float xm_l[NB*18];           // (x,m) float2 pairs, stride 18
    __shared__ float gx_l[NB*9];            // gamma_x, stride 9
    __shared__ float impbuf[NB*IMPST];      // 16-step imputation buffer (fp32)
    __shared__ float red[8];

    const int tid  = threadIdx.x;
    const int b0   = blockIdx.x * NB;
    const int lane = tid & 63;
    const int w    = tid >> 6;      // wave 0..7
    const int quad = lane >> 4;
    const int l15  = lane & 15;

    // ---- one-time LDS init ----
    for (int i = tid; i < NB*168; i += NTHR) hbuf[i] = 0;
    for (int i = tid; i < NB*32;  i += NTHR) bbuf[i] = 0;
    for (int i = tid; i < 8*NB*8; i += NTHR) xh_part[i] = 0.f;
    if (tid < 8) zpad[tid] = 0;
    __syncthreads();                 // zeros visible before bias-column pokes
    if (tid < NB) {
        bbuf[tid*32 + 7]  = 0x3F80;  // 1.0 -> gate-bias column
        bbuf[tid*32 + 15] = 0x3F80;  // 1.0 -> decay-bias column
    }

    // ---- persistent weight fragments (per lane), exp-folded scales ----
    short8 whhf[4][4];   // [gate c][kstep]  A[j=l15 of tile][k=quad*8+e]
    short8 winf_c[4];    // c_c part: k0..6 = W_ih[:,0..6]*sc, rest 0
    short8 winf_mb[4];   // m part:   k0..6 = W_ih[:,7..13]*sc, k7 = bias*sc
    short8 wtdf;         // decay:    k8..14 = W_td_h*L2E, k15 = b_td_h*L2E
    short8 wxf;          // x_h partial: A[i=l15<7][k<16] = W_hist[i][w*16+k]
    {
        const float scg[4] = { L2E, L2E, TL2E, L2E };   // i,f,g,o
        union UU { short8 v; unsigned short u[8]; } fr;
        #pragma unroll
        for (int c = 0; c < 4; ++c) {
            const float sc = scg[c];
            const int j = (c*8 + w)*16 + l15;
            #pragma unroll
            for (int s = 0; s < 4; ++s) {
                const float* p = W_hh + j*H_ + s*32 + quad*8;
                #pragma unroll
                for (int e = 0; e < 8; ++e) fr.u[e] = f2bf(p[e] * sc);
                whhf[c][s] = fr.v;
            }
            #pragma unroll
            for (int e = 0; e < 8; ++e) {
                int k = quad*8 + e;
                fr.u[e] = (k < 7) ? f2bf(W_ih[j*14 + k] * sc) : (unsigned short)0;
            }
            winf_c[c] = fr.v;
            #pragma unroll
            for (int e = 0; e < 8; ++e) {
                int k = quad*8 + e;
                float v = (k < 7) ? W_ih[j*14 + 7 + k]
                        : ((k == 7) ? (b_ih[j] + b_hh[j]) : 0.f);
                fr.u[e] = f2bf(v * sc);
            }
            winf_mb[c] = fr.v;
        }
        const int j2 = w*16 + l15;
        #pragma unroll
        for (int e = 0; e < 8; ++e) {
            int k = quad*8 + e;
            float v = (k >= 8 && k < 15) ? W_td_h[j2*D_ + (k - 8)]
                    : ((k == 15) ? b_td_h[j2] : 0.f);
            fr.u[e] = f2bf(v * L2E);
        }
        wtdf = fr.v;
        #pragma unroll
        for (int e = 0; e < 8; ++e) {
            int k = quad*8 + e;
            fr.u[e] = (l15 < 7 && k < 16) ? f2bf(W_hist[l15*H_ + w*16 + k])
                                          : (unsigned short)0;
        }
        wxf = fr.v;
    }

    // ---- A3/stager threads: 28 lanes per wave, 4 batch rows per wave ----
    const int l7q = lane / 7, l7r = lane - l7q*7;
    const bool athr = (lane < 28);
    const int arow = w*4 + l7q;              // batch row 0..31
    const int afeat = l7r;                   // feature 0..6
    float wfr[7], wcr[14], bfr = 0.f, bcr = 0.f;
    float tdx_own = 0.f, btdx_own = 0.f, bh_own = 0.f;
    if (athr) {
        #pragma unroll
        for (int k = 0; k < 7; ++k)  wfr[k] = (k == afeat) ? 0.f : W_feat[afeat*D_ + k];
        #pragma unroll
        for (int k = 0; k < 14; ++k) wcr[k] = W_comb[afeat*14 + k];
        bfr = b_feat[afeat];  bcr = b_comb[afeat];
        tdx_own = W_td_x[afeat*D_ + afeat] * L2E;
        btdx_own = b_td_x[afeat] * L2E;
        bh_own = b_hist[afeat];
    }

    float c_st[2][4] = {{0,0,0,0},{0,0,0,0}};
    float lacc = 0.f;

    // input prefetch (regs hold step-t data at loop top)
    const long gbase = (long)(b0 + arow)*TD_ + afeat;
    float rx = 0.f, rm = 0.f, rd = 0.f;
    if (athr) { rx = values[gbase]; rm = masks[gbase]; rd = deltas[gbase]; }

    const float* msums = ws + WS_MINV;

    for (int t = 0; t < T_; ++t) {
        float x_cur = rx, m_cur = rm;
        // ---- stage: x,m pair; gamma_x (own exp); m -> bbuf ----
        if (athr) {
            float2 s2 = { rx, rm };
            *(float2*)&xm_l[arow*18 + 2*afeat] = s2;
            gx_l[arow*9 + afeat] = expn2_(fmaxf(fmaf(rd, tdx_own, btdx_own), 0.f));
            bbuf[arow*32 + afeat] = f2bf(rm);
        }
        BARRIER();                             // [S] h/xh_part(t) + stage visible
        if (athr && t + 1 < T_) {
            const long g = gbase + (long)(t+1)*D_;
            rx = values[g]; rm = masks[g]; rd = deltas[g];
            bbuf[arow*32 + 8 + afeat] = f2bf(rd);   // d(t+1) (zero-weight cols for P12 readers)
        }

        // ---- P12: gate-h + m/bias MFMAs, overlapped with A3 ----
        floatx4 acc[4][2];
        #pragma unroll
        for (int c = 0; c < 4; ++c)
            #pragma unroll
            for (int nt = 0; nt < 2; ++nt) { floatx4 z = {0,0,0,0}; acc[c][nt] = z; }
        #pragma unroll
        for (int s = 0; s < 4; ++s) {
            short8 hb0 = *(const short8*)&hbuf[l15*168       + s*32 + quad*8];
            short8 hb1 = *(const short8*)&hbuf[(16+l15)*168  + s*32 + quad*8];
            #pragma unroll
            for (int c = 0; c < 4; ++c) {
                acc[c][0] = MFMA16(whhf[c][s], hb0, acc[c][0]);
                acc[c][1] = MFMA16(whhf[c][s], hb1, acc[c][1]);
            }
        }
        {
            short8 bb0 = *(const short8*)&bbuf[l15*32      + quad*8];
            short8 bb1 = *(const short8*)&bbuf[(16+l15)*32 + quad*8];
            #pragma unroll
            for (int c = 0; c < 4; ++c) {
                acc[c][0] = MFMA16(winf_mb[c], bb0, acc[c][0]);
                acc[c][1] = MFMA16(winf_mb[c], bb1, acc[c][1]);
            }
        }

        // ---- A3 (28 lanes/wave): sum xh partials, bpermute-share, body ----
        if (athr) {
            float xh8 = bh_own;
            #pragma unroll
            for (int q = 0; q < 8; ++q) xh8 += xh_part[q*(NB*8) + arow*8 + afeat];
            const float invt = rcp_(msums[t] + 1e-5f);
            const int bl4 = l7q * 7;           // base lane of this row's 7-group
            float zh = bfr, al = bcr;
            #pragma unroll
            for (int k = 0; k < 7; ++k) {
                float xhk = __builtin_bit_cast(float,
                    __builtin_amdgcn_ds_bpermute((bl4 + k) << 2,
                        __builtin_bit_cast(int, xh8)));
                float2 xm2 = *(const float2*)&xm_l[arow*18 + 2*k];
                float xck = xm2.y*xm2.x + (1.f - xm2.y)*xhk;
                zh = fmaf(wfr[k], xck, zh);
                al = fmaf(wcr[k], gx_l[arow*9 + k], al);
                al = fmaf(wcr[7+k], xm2.y, al);
            }
            const float ch = al*zh + (1.f - al)*xh8;
            const float cc = m_cur*x_cur + (1.f - m_cur)*ch;
            impbuf[arow*IMPST + (t & 15)*7 + afeat] = cc;
            hbuf[arow*168 + 128 + afeat] = f2bf(cc);
            lacc = fmaf((fabsf(x_cur-xh8) + fabsf(x_cur-zh) + fabsf(x_cur-ch)) * m_cur,
                        invt, lacc);
        }
        BARRIER();                             // [C] c_c ext ready

        // ---- P3: c_c MFMA + decay MFMA + LSTM + h write + xh partial ----
        {
            short8 ib0 = *(const short8*)&hbuf[l15*168      + 128 + quad*8];
            short8 ib1 = *(const short8*)&hbuf[(16+l15)*168 + 128 + quad*8];
            #pragma unroll
            for (int c = 0; c < 4; ++c) {
                acc[c][0] = MFMA16(winf_c[c], ib0, acc[c][0]);
                acc[c][1] = MFMA16(winf_c[c], ib1, acc[c][1]);
            }
        }
        const bool dec = (t + 1 < T_);
        floatx4 g0 = {0,0,0,0}, g1 = {0,0,0,0};
        if (dec) {
            short8 bb0 = *(const short8*)&bbuf[l15*32      + quad*8];
            short8 bb1 = *(const short8*)&bbuf[(16+l15)*32 + quad*8];
            floatx4 z = {0,0,0,0};
            g0 = MFMA16(wtdf, bb0, z);
            g1 = MFMA16(wtdf, bb1, z);
        }
        #pragma unroll
        for (int nt = 0; nt < 2; ++nt) {
            const int b = nt*16 + l15;
            floatx4 gg = nt ? g1 : g0;
            float hnv[4];
            #pragma unroll
            for (int r = 0; r < 4; ++r) {
                float ig = acc[0][nt][r], fg = acc[1][nt][r];
                float gv = acc[2][nt][r], og = acc[3][nt][r];
                float si = rcp_(1.f + expn2_(ig));
                float sf = rcp_(1.f + expn2_(fg));
                float tg = 1.f - 2.f*rcp_(1.f + exp2_(gv));
                float cn = sf*c_st[nt][r] + si*tg;
                c_st[nt][r] = cn;
                float so = rcp_(1.f + expn2_(og));
                float th = 1.f - 2.f*rcp_(1.f + exp2_(cn*TL2E));
                float hn = so*th;
                if (dec) hn *= expn2_(fmaxf(gg[r], 0.f));
                hnv[r] = hn;
            }
            uint2 pk;
            pk.x = (unsigned)f2bf(hnv[0]) | ((unsigned)f2bf(hnv[1]) << 16);
            pk.y = (unsigned)f2bf(hnv[2]) | ((unsigned)f2bf(hnv[3]) << 16);
            *(uint2*)&hbuf[b*168 + w*16 + quad*4] = pk;
        }
        // per-wave partial x_h(t+1) over own 16 h-columns (K=16 + 16 zero)
        if (dec) {
            const unsigned short* a0 = (quad < 2)
                ? &hbuf[l15*168      + w*16 + quad*8] : zpad;
            const unsigned short* a1 = (quad < 2)
                ? &hbuf[(16+l15)*168 + w*16 + quad*8] : zpad;
            short8 hb0 = *(const short8*)a0;
            short8 hb1 = *(const short8*)a1;
            floatx4 z = {0,0,0,0};
            floatx4 p0 = MFMA16(wxf, hb0, z);
            floatx4 p1 = MFMA16(wxf, hb1, z);
            if (quad < 2) {
                floatx4 q0 = p0, q1 = p1;
                *(floatx4*)&xh_part[w*(NB*8) + l15*8      + quad*4] = q0;
                *(floatx4*)&xh_part[w*(NB*8) + (16+l15)*8 + quad*4] = q1;
            }
        }

        // ---- imputation flush (contiguous 28B runs, 16 steps at a time) ----
        if ((t & 15) == 15 || t == T_ - 1) {
            const int t0 = t & ~15;
            const int b  = tid >> 4, c16 = tid & 15;
            if (t0 + c16 <= t) {
                float* gp = out + (size_t)OUT_IMP + (size_t)(b0+b)*TD_ + (size_t)(t0+c16)*D_;
                const float* lp = &impbuf[b*IMPST + c16*7];
                #pragma unroll
                for (int e = 0; e < 7; ++e) gp[e] = lp[e];
            }
        }
    }
    BARRIER();

    // ---- x_loss partial reduction ----
    for (int off = 32; off > 0; off >>= 1) lacc += __shfl_down(lacc, off, 64);
    if ((tid & 63) == 0) red[tid >> 6] = lacc;
    __syncthreads();
    if (tid == 0) {
        float s = 0.f;
        #pragma unroll
        for (int q = 0; q < 8; ++q) s += red[q];
        atomicAdd(&ws[WS_ACC], s);
    }
    // ---- final h -> workspace (fp32) ----
    for (int i = tid; i < NB*H_; i += NTHR) {
        int b = i >> 7, j = i & 127;
        ws[WS_HFIN + (size_t)(b0+b)*H_ + j] = bf2f(hbuf[b*168 + j]);
    }
}

// ================= classification head =================
__global__ __launch_bounds__(128) void rits_head(
    const float* __restrict__ probs, const float* __restrict__ ancillary, const int* __restrict__ labels,
    const float* __restrict__ W_anc, const float* __restrict__ b_anc,
    const float* __restrict__ b_cat,
    const float* __restrict__ W_out, const float* __restrict__ b_out,
    float* __restrict__ ws, float* __restrict__ out)
{
    __shared__ float hb[MB*H_];
    __shared__ float ancl[MB*52];
    __shared__ float hc[MB*H_];
    __shared__ float lg[MB*32];
    __shared__ float smx[MB], sinv[MB], ysum[MB];
    __shared__ float sq[MB*32];
    const int tid = threadIdx.x;
    const int bb0 = blockIdx.x * MB;

    for (int i = tid; i < MB*H_; i += 128) hb[i] = ws[WS_HFIN + (size_t)bb0*H_ + i];
    for (int i = tid; i < MB*E_; i += 128) {
        int b = i / E_, e = i - b*E_;
        float s = b_anc[e];
        #pragma unroll
        for (int a = 0; a < A_; ++a) s = fmaf(ancillary[(bb0+b)*A_ + a], W_anc[e*A_ + a], s);
        ancl[b*52+e] = fmaxf(s, 0.f);
    }
    __syncthreads();
    {
        const int j = tid;
        float s[MB];
        #pragma unroll
        for (int b = 0; b < MB; ++b) s[b] = b_cat[j];
        const float* wc = ws + WS_WCATT;
        for (int k = 0; k < H_; ++k) {
            float wv = wc[k*H_ + j];
            #pragma unroll
            for (int b = 0; b < MB; ++b) s[b] = fmaf(hb[b*H_+k], wv, s[b]);
        }
        for (int k = 0; k < E_; ++k) {
            float wv = wc[(H_+k)*H_ + j];
            #pragma unroll
            for (int b = 0; b < MB; ++b) s[b] = fmaf(ancl[b*52+k], wv, s[b]);
        }
        #pragma unroll
        for (int b = 0; b < MB; ++b) hc[b*H_+j] = fmaxf(s[b], 0.f);
    }
    __syncthreads();
    for (int i = tid; i < MB*O_; i += 128) {
        int b = i / O_, o = i - b*O_;
        float s = b_out[o];
        for (int k = 0; k < H_; ++k) s = fmaf(hc[b*H_+k], W_out[o*H_+k], s);
        lg[b*32+o] = s;
    }
    __syncthreads();
    if (tid < MB) {
        float mx = -1e30f;
        for (int o = 0; o < O_; ++o) mx = fmaxf(mx, lg[tid*32+o]);
        float se = 0.f;
        for (int o = 0; o < O_; ++o) se += __expf(lg[tid*32+o] - mx);
        smx[tid] = mx; sinv[tid] = 1.f / se;
    }
    __syncthreads();
    for (int i = tid; i < MB*O_; i += 128) {
        int b = i / O_, o = i - b*O_;
        float y = __expf(lg[b*32+o] - smx[b]) * sinv[b];
        out[OUT_YH + (size_t)(bb0+b)*O_ + o] = y;
        float d = y - probs[(size_t)(bb0+b)*O_ + o];
        sq[b*32+o] = d*d;
    }
    __syncthreads();
    if (tid < MB) {
        float s = 0.f;
        for (int o = 0; o < O_; ++o) s += sq[tid*32+o];
        ysum[tid] = s;
        out[OUT_LAB + bb0 + tid] = (float)labels[bb0 + tid];
    }
    __syncthreads();
    if (tid == 0) {
        float s = 0.f;
        #pragma unroll
        for (int b = 0; b < MB; ++b) s += ysum[b];
        atomicAdd(&ws[WS_ACC+1], s);
    }
}

// ================= finalize scalars =================
__global__ void rits_fin(const float* __restrict__ ws, float* __restrict__ out)
{
    if (blockIdx.x == 0 && threadIdx.x == 0) {
        float xl = ws[WS_ACC] * 0.3f;
        float yl = ws[WS_ACC+1] * (1.0f / (8192.0f + 1e-5f));
        out[0] = xl; out[1] = yl; out[2] = xl + yl;
    }
}

extern "C" void kernel_launch(void* const* d_in, const int* in_sizes, int n_in,
                              void* d_out, int out_size, void* d_ws, size_t ws_size,
                              hipStream_t stream)
{
    const float* values = (const float*)d_in[0];
    const float* masks  = (const float*)d_in[1];
    const float* deltas = (const float*)d_in[2];
    const float* probs  = (const float*)d_in[3];
    const float* ancil  = (const float*)d_in[4];
    const int*   labels = (const int*)  d_in[5];
    const float* W_td_h = (const float*)d_in[6];
    const float* b_td_h = (const float*)d_in[7];
    const float* W_td_x = (const float*)d_in[8];
    const float* b_td_x = (const float*)d_in[9];
    const float* W_hist = (const float*)d_in[10];
    const float* b_hist = (const float*)d_in[11];
    const float* W_feat = (const float*)d_in[12];
    const float* b_feat = (const float*)d_in[13];
    const float* W_comb = (const float*)d_in[14];
    const float* b_comb = (const float*)d_in[15];
    const float* W_ih   = (const float*)d_in[16];
    const float* W_hh   = (const float*)d_in[17];
    const float* b_ih   = (const float*)d_in[18];
    const float* b_hh   = (const float*)d_in[19];
    const float* W_anc  = (const float*)d_in[20];
    const float* b_anc  = (const float*)d_in[21];
    const float* W_cat  = (const float*)d_in[22];
    const float* b_cat  = (const float*)d_in[23];
    const float* W_out  = (const float*)d_in[24];
    const float* b_out  = (const float*)d_in[25];
    float* ws  = (float*)d_ws;
    float* out = (float*)d_out;

    hipLaunchKernelGGL(rits_prep, dim3((H_*178 + 255)/256), dim3(256), 0, stream, W_cat, ws);
    hipLaunchKernelGGL(rits_msum, dim3(7*MS_BG), dim3(256), 0, stream, masks, ws);
    hipLaunchKernelGGL(rits_main, dim3(B_/NB), dim3(NTHR), 0, stream,
                       values, masks, deltas, W_td_h, b_td_h, W_td_x, b_td_x,
                       W_hist, b_hist, W_feat, b_feat, W_comb, b_comb,
                       W_ih, W_hh, b_ih, b_hh, ws, out);
    hipLaunchKernelGGL(rits_head, dim3(B_/MB), dim3(128), 0, stream,
                       probs, ancil, labels, W_anc, b_anc, b_cat, W_out, b_out, ws, out);
    hipLaunchKernelGGL(rits_fin, dim3(1), dim3(1), 0, stream, ws, out);
}

// Round 7
// 875.294 us; speedup vs baseline: 1.1109x; 1.1109x over previous
//
#include <hip/hip_runtime.h>
#include <math.h>

// ---------------- problem constants ----------------
#define B_ 8192
#define T_ 223
#define D_ 7
#define H_ 128
#define E_ 50
#define O_ 29
#define A_ 9
#define TD_ (T_*D_)     // 1561
#define NB 32           // batch rows per block (main kernel) -> grid 256 = 1 block/CU
#define NTHR 512
#define MB 8            // batch rows per block (head kernel)
#define MS_BG 128       // msum batch groups

// ---------------- workspace layout (float offsets) ----------------
#define WS_MINV  0                            // raw msum_t sums, T floats
#define WS_ACC   (WS_MINV + T_)               // [0]=x_loss raw sum, [1]=y_loss raw sum
#define WS_WCATT (WS_ACC + 2)                 // [178][128] transposed W_cat
#define WS_HFIN  (WS_WCATT + 178*H_)          // final h, [B][128] fp32

// ---------------- output layout (floats) ----------------
#define OUT_YH  3
#define OUT_IMP (OUT_YH + B_*O_)              // 237571
#define OUT_LAB (OUT_IMP + B_*T_*D_)          // 13025283

typedef __attribute__((ext_vector_type(8))) short short8;   // 8 bf16 = 4 VGPRs
typedef __attribute__((ext_vector_type(4))) float floatx4;
#define MFMA16(Av,Bv,Cv) __builtin_amdgcn_mfma_f32_16x16x32_bf16((Av),(Bv),(Cv),0,0,0)

// raw barrier: drain LDS only (producer/consumer ordering); do NOT drain
// vmcnt -- global prefetch loads ride across and land during the next phase.
#define BARRIER() do { asm volatile("s_waitcnt lgkmcnt(0)" ::: "memory"); \
                       __builtin_amdgcn_s_barrier(); } while (0)

__device__ __forceinline__ unsigned short f2bf(float f) {   // RNE fp32->bf16
    unsigned int u = __builtin_bit_cast(unsigned int, f);
    return (unsigned short)((u + 0x7FFFu + ((u >> 16) & 1u)) >> 16);
}
__device__ __forceinline__ float bf2f(unsigned short s) {
    unsigned int u = ((unsigned int)s) << 16;
    return __builtin_bit_cast(float, u);
}
__device__ __forceinline__ float rcp_(float x)  { return __builtin_amdgcn_rcpf(x); }
__device__ __forceinline__ float sigm(float x)  { return rcp_(1.f + __expf(-x)); }
__device__ __forceinline__ float tanh_(float x) { return 1.f - 2.f*rcp_(1.f + __expf(2.f*x)); }

// ================= prep: W_cat transpose + zero accumulators =================
__global__ void rits_prep(const float* __restrict__ W_cat, float* __restrict__ ws)
{
    int idx = blockIdx.x * 256 + threadIdx.x;
    if (idx < H_*178) {                      // W_cat [128][178] -> [178][128]
        int j = idx / 178, k = idx - j*178;
        ws[WS_WCATT + k*H_ + j] = W_cat[idx];
    }
    if (idx < T_) ws[WS_MINV + idx] = 0.f;
    if (idx < 2) ws[WS_ACC + idx] = 0.f;
}

// ================= per-step mask sums (coalesced, atomic partials) =================
__global__ void rits_msum(const float* __restrict__ masks, float* __restrict__ ws)
{
    const int tc = blockIdx.x % 7;           // t-chunk of 32 steps
    const int bg = blockIdx.x / 7;           // batch group
    const int t0 = tc * 32;
    const int nt = (t0 + 32 <= T_) ? 32 : (T_ - t0);
    const int ncol = nt * D_;                // 224 or 217
    const int tid = threadIdx.x;
    __shared__ float sums[224];
    float s = 0.f;
    if (tid < ncol) {
        const int bpg = B_ / MS_BG;          // 64
        const float* p = masks + (size_t)bg * bpg * TD_ + (size_t)t0 * D_ + tid;
        #pragma unroll 4
        for (int b = 0; b < bpg; ++b) s += p[(size_t)b * TD_];
    }
    if (tid < 224) sums[tid] = (tid < ncol) ? s : 0.f;
    __syncthreads();
    if (tid < 32) {
        float r = 0.f;
        #pragma unroll
        for (int q = 0; q < 7; ++q) r += sums[tid*7 + q];
        if (t0 + tid < T_) atomicAdd(&ws[WS_MINV + t0 + tid], r);
    }
}

// ================= main scan kernel (MFMA) =================
// R5 structure (751us, absmax 0.0078) with ONE isolated change: raw
// lgkm-only barriers + prefetch issued before [S] so global loads ride
// across barriers (no vmcnt(0) drain -> no ~600cy HBM stall at [B]).
//  [S] -> I1: gate-h MFMAs + wave7 x_h MFMAs + float2 publish.
//  [B] -> I2: m/bias MFMA; A3 (waves 0-3) incl. bbuf-d write (d(t+1)
//             prefetched at loop-top, ~1300cy to land).
//  [C] -> I3: c_c MFMA + decay MFMA + LSTM + h write (+ imp flush).
// msums[t] prefetched into a register one step ahead (off A3 critical path).
__global__ __launch_bounds__(NTHR, 2) void rits_main(
    const float* __restrict__ values, const float* __restrict__ masks, const float* __restrict__ deltas,
    const float* __restrict__ W_td_h, const float* __restrict__ b_td_h,
    const float* __restrict__ W_td_x, const float* __restrict__ b_td_x,
    const float* __restrict__ W_hist, const float* __restrict__ b_hist,
    const float* __restrict__ W_feat, const float* __restrict__ b_feat,
    const float* __restrict__ W_comb, const float* __restrict__ b_comb,
    const float* __restrict__ W_ih, const float* __restrict__ W_hh,
    const float* __restrict__ b_ih, const float* __restrict__ b_hh,
    float* __restrict__ ws, float* __restrict__ out)
{
    // hbuf row (bf16, stride 168): 0..127 h, 128..134 c_c, 135..159 zeros
    __shared__ __attribute__((aligned(16))) unsigned short hbuf[NB*168];
    // bbuf row (bf16, stride 32): 0..6 m(t), 7=1.0, 8..14 d(t+1), 15=1.0, 16..31=0
    __shared__ __attribute__((aligned(16))) unsigned short bbuf[NB*32];
    __shared__ __attribute__((aligned(16))) unsigned short whis_lds[16*136]; // W_hist bf16, rows 7..15 = 0
    __shared__ float xm_l[NB*18];           // (x,m) float2 pairs, stride 18 (conflict-free)
    __shared__ float gx_l[NB*9];            // gamma_x, stride 9
    __shared__ float xh_l[NB*10];           // x_h raw (bias added), stride 10, float2-aligned
    __shared__ float impbuf[NB*16*7];       // 16-step imputation buffer (fp32)
    __shared__ float red[8];

    const int tid  = threadIdx.x;
    const int b0   = blockIdx.x * NB;
    const int lane = tid & 63;
    const int w    = tid >> 6;      // wave 0..7
    const int quad = lane >> 4;
    const int l15  = lane & 15;

    // ---- one-time LDS init ----
    for (int i = tid; i < NB*168; i += NTHR) hbuf[i] = 0;
    for (int i = tid; i < NB*32;  i += NTHR) bbuf[i] = 0;
    for (int i = tid; i < 16*136; i += NTHR) {
        int r = i / 136, c = i - r*136;
        whis_lds[i] = (r < 7 && c < 128) ? f2bf(W_hist[r*H_ + c]) : 0;
    }
    __syncthreads();                 // zeros visible before bias-column pokes
    if (tid < NB) {
        bbuf[tid*32 + 7]  = 0x3F80;  // 1.0 -> gate-bias column
        bbuf[tid*32 + 15] = 0x3F80;  // 1.0 -> decay-bias column
    }

    // ---- persistent weight fragments (per lane) ----
    short8 whhf[4][4];   // [gate c][kstep]  A[j=l15 of tile][k=quad*8+e]
    short8 winf_c[4];    // c_c part: k0..6 = W_ih[:, 0..6], rest 0
    short8 winf_mb[4];   // m part:   k0..6 = W_ih[:, 7..13], k7 = b_ih+b_hh, rest 0
    short8 wtdf;         // decay:    k8..14 = W_td_h, k15 = b_td_h, rest 0
    float  bh_r[4];      // b_hist for wave7 publish
    {
        union UU { short8 v; unsigned short u[8]; } fr;
        #pragma unroll
        for (int c = 0; c < 4; ++c) {
            const int j = (c*8 + w)*16 + l15;
            #pragma unroll
            for (int s = 0; s < 4; ++s) {
                const float* p = W_hh + j*H_ + s*32 + quad*8;
                #pragma unroll
                for (int e = 0; e < 8; ++e) fr.u[e] = f2bf(p[e]);
                whhf[c][s] = fr.v;
            }
            #pragma unroll
            for (int e = 0; e < 8; ++e) {
                int k = quad*8 + e;
                fr.u[e] = (k < 7) ? f2bf(W_ih[j*14 + k]) : (unsigned short)0;
            }
            winf_c[c] = fr.v;
            #pragma unroll
            for (int e = 0; e < 8; ++e) {
                int k = quad*8 + e;
                float v = (k < 7) ? W_ih[j*14 + 7 + k]
                        : ((k == 7) ? (b_ih[j] + b_hh[j]) : 0.f);
                fr.u[e] = f2bf(v);
            }
            winf_mb[c] = fr.v;
        }
        const int j2 = w*16 + l15;
        #pragma unroll
        for (int e = 0; e < 8; ++e) {
            int k = quad*8 + e;
            float v = (k >= 8 && k < 15) ? W_td_h[j2*D_ + (k - 8)]
                    : ((k == 15) ? b_td_h[j2] : 0.f);
            fr.u[e] = f2bf(v);
        }
        wtdf = fr.v;
        #pragma unroll
        for (int r = 0; r < 4; ++r) {
            int f = quad*4 + r;
            bh_r[r] = (quad < 2 && f < 7) ? b_hist[f] : 0.f;
        }
    }

    // ---- A3 per-thread state ----
    const bool ldr = (tid < NB*D_);
    const int  lb  = tid / D_, li = tid - (tid/D_)*D_;
    float wfr[7], wcr[14], bfr = 0.f, bcr = 0.f, tdx_own = 0.f, btdx_own = 0.f;
    if (ldr) {
        #pragma unroll
        for (int k = 0; k < 7; ++k)  wfr[k] = (k == li) ? 0.f : W_feat[li*D_ + k];
        #pragma unroll
        for (int k = 0; k < 14; ++k) wcr[k] = W_comb[li*14 + k];
        bfr = b_feat[li];  bcr = b_comb[li];
        tdx_own = W_td_x[li*D_ + li];  btdx_own = b_td_x[li];
    }

    float c_st[2][4] = {{0,0,0,0},{0,0,0,0}};
    float lacc = 0.f;

    // input prefetch (regs hold step-t data at loop top)
    const long gbase = (long)(b0 + lb)*TD_ + li;
    float rx = 0.f, rm = 0.f, rd = 0.f;
    const float* msums = ws + WS_MINV;
    float rmv = 0.f;
    if (ldr) { rx = values[gbase]; rm = masks[gbase]; rd = deltas[gbase]; rmv = msums[0]; }

    for (int t = 0; t < T_; ++t) {
        // ---- stage step-t data (consumes rx/rm/rd), then ISSUE t+1 loads ----
        if (ldr) {
            float2 s2 = { rx, rm };
            *(float2*)&xm_l[lb*18 + 2*li] = s2;
            gx_l[lb*9 + li] = __expf(-fmaxf(fmaf(rd, tdx_own, btdx_own), 0.f));
            bbuf[lb*32 + li] = f2bf(rm);
            if (t + 1 < T_) {
                const long g = gbase + (long)(t+1)*D_;
                rx = values[g]; rm = masks[g]; rd = deltas[g];   // ride across [S]
                rmv = msums[t+1] ;                               // note: used NEXT step
            }
        }
        const float invt = rcp_((ldr ? (t ? rmv : msums[t]) : 0.f) + 1e-5f);
        BARRIER();                             // [S] stage + prev h-writes visible (LDS only)

        // ---- I1: gate h-part (+ x_h on wave 7). h in hbuf is ALREADY decayed ----
        floatx4 acc[4][2];
        #pragma unroll
        for (int c = 0; c < 4; ++c)
            #pragma unroll
            for (int nt = 0; nt < 2; ++nt) { floatx4 z = {0,0,0,0}; acc[c][nt] = z; }
        floatx4 xh0 = {0,0,0,0}, xh1 = {0,0,0,0};
        #pragma unroll
        for (int s = 0; s < 4; ++s) {
            short8 hb0 = *(const short8*)&hbuf[l15*168       + s*32 + quad*8];
            short8 hb1 = *(const short8*)&hbuf[(16+l15)*168  + s*32 + quad*8];
            #pragma unroll
            for (int c = 0; c < 4; ++c) {
                acc[c][0] = MFMA16(whhf[c][s], hb0, acc[c][0]);
                acc[c][1] = MFMA16(whhf[c][s], hb1, acc[c][1]);
            }
            if (w == 7) {
                short8 wh = *(const short8*)&whis_lds[l15*136 + s*32 + quad*8];
                xh0 = MFMA16(wh, hb0, xh0);
                xh1 = MFMA16(wh, hb1, xh1);
            }
        }
        // wave 7: publish raw x_h (bias added) as float2 pairs — short tail
        if (w == 7 && quad < 2) {
            #pragma unroll
            for (int nt = 0; nt < 2; ++nt) {
                const int b = nt*16 + l15;
                floatx4 xv = nt ? xh1 : xh0;
                float2 p0 = { xv[0] + bh_r[0], xv[1] + bh_r[1] };
                float2 p1 = { xv[2] + bh_r[2], xv[3] + bh_r[3] };
                *(float2*)&xh_l[b*10 + quad*4]     = p0;
                *(float2*)&xh_l[b*10 + quad*4 + 2] = p1;
            }
        }
        BARRIER();                             // [B] x_h ready

        // ---- I2: m-part + gate-bias MFMAs (all waves) ----
        {
            short8 bb0 = *(const short8*)&bbuf[l15*32      + quad*8];
            short8 bb1 = *(const short8*)&bbuf[(16+l15)*32 + quad*8];
            #pragma unroll
            for (int c = 0; c < 4; ++c) {
                acc[c][0] = MFMA16(winf_mb[c], bb0, acc[c][0]);
                acc[c][1] = MFMA16(winf_mb[c], bb1, acc[c][1]);
            }
        }

        // ---- A3: z_h, alpha, c_h, c_c, imputation, loss; + bbuf-d write ----
        if (ldr) {
            const int b = lb, i = li;
            const float x = xm_l[b*18 + 2*i], m = xm_l[b*18 + 2*i + 1];
            const float xhv = xh_l[b*10 + i];
            float zh = bfr, al = bcr;
            #pragma unroll
            for (int k = 0; k < 7; ++k) {
                const float xk  = xm_l[b*18 + 2*k];
                const float mk  = xm_l[b*18 + 2*k + 1];
                const float xhk = xh_l[b*10 + k];
                const float xck = mk*xk + (1.f - mk)*xhk;
                zh = fmaf(wfr[k], xck, zh);
                al = fmaf(wcr[k], gx_l[b*9 + k], al);
                al = fmaf(wcr[7+k], mk, al);
            }
            const float ch = al*zh + (1.f - al)*xhv;
            const float cc = m*x + (1.f - m)*ch;
            impbuf[(b*16 + (t & 15))*7 + i] = cc;
            hbuf[b*168 + 128 + i] = f2bf(cc);
            lacc = fmaf((fabsf(x-xhv) + fabsf(x-zh) + fabsf(x-ch)) * m, invt, lacc);
            if (t + 1 < T_)
                bbuf[lb*32 + 8 + li] = f2bf(rd);   // d(t+1), prefetched at loop-top
        }
        BARRIER();                             // [C] c_c ext + bbuf-d ready

        // ---- I3: c_c-part MFMA + decay MFMA ----
        {
            short8 ib0 = *(const short8*)&hbuf[l15*168      + 128 + quad*8];
            short8 ib1 = *(const short8*)&hbuf[(16+l15)*168 + 128 + quad*8];
            #pragma unroll
            for (int c = 0; c < 4; ++c) {
                acc[c][0] = MFMA16(winf_c[c], ib0, acc[c][0]);
                acc[c][1] = MFMA16(winf_c[c], ib1, acc[c][1]);
            }
        }
        const bool dec = (t + 1 < T_);
        floatx4 g0 = {0,0,0,0}, g1 = {0,0,0,0};
        if (dec) {
            short8 bb0 = *(const short8*)&bbuf[l15*32      + quad*8];
            short8 bb1 = *(const short8*)&bbuf[(16+l15)*32 + quad*8];
            floatx4 z = {0,0,0,0};
            g0 = MFMA16(wtdf, bb0, z);
            g1 = MFMA16(wtdf, bb1, z);
        }
        // ---- LSTM update; write h (pre-decayed for next step) as b64 ----
        #pragma unroll
        for (int nt = 0; nt < 2; ++nt) {
            const int b = nt*16 + l15;
            floatx4 gg = nt ? g1 : g0;
            float hnv[4];
            #pragma unroll
            for (int r = 0; r < 4; ++r) {
                float ig = acc[0][nt][r], fg = acc[1][nt][r];
                float gv = acc[2][nt][r], og = acc[3][nt][r];
                float cn = sigm(fg)*c_st[nt][r] + sigm(ig)*tanh_(gv);
                c_st[nt][r] = cn;
                float hn = sigm(og)*tanh_(cn);
                if (dec) hn *= __expf(-fmaxf(gg[r], 0.f));
                hnv[r] = hn;
            }
            uint2 pk;
            pk.x = (unsigned)f2bf(hnv[0]) | ((unsigned)f2bf(hnv[1]) << 16);
            pk.y = (unsigned)f2bf(hnv[2]) | ((unsigned)f2bf(hnv[3]) << 16);
            *(uint2*)&hbuf[b*168 + w*16 + quad*4] = pk;
        }

        // ---- imputation flush (contiguous 28B runs, 16 steps at a time) ----
        if ((t & 15) == 15 || t == T_ - 1) {
            const int t0 = t & ~15;
            const int b  = tid >> 4, c16 = tid & 15;
            if (t0 + c16 <= t) {
                float* gp = out + (size_t)OUT_IMP + (size_t)(b0+b)*TD_ + (size_t)(t0+c16)*D_;
                const float* lp = &impbuf[(b*16 + c16)*7];
                #pragma unroll
                for (int e = 0; e < 7; ++e) gp[e] = lp[e];
            }
        }
    }
    __syncthreads();

    // ---- x_loss partial reduction ----
    for (int off = 32; off > 0; off >>= 1) lacc += __shfl_down(lacc, off, 64);
    if ((tid & 63) == 0) red[tid >> 6] = lacc;
    __syncthreads();
    if (tid == 0) {
        float s = 0.f;
        #pragma unroll
        for (int q = 0; q < 8; ++q) s += red[q];
        atomicAdd(&ws[WS_ACC], s);
    }
    // ---- final h -> workspace (fp32) ----
    for (int i = tid; i < NB*H_; i += NTHR) {
        int b = i >> 7, j = i & 127;
        ws[WS_HFIN + (size_t)(b0+b)*H_ + j] = bf2f(hbuf[b*168 + j]);
    }
}

// ================= classification head =================
__global__ __launch_bounds__(128) void rits_head(
    const float* __restrict__ probs, const float* __restrict__ ancillary, const int* __restrict__ labels,
    const float* __restrict__ W_anc, const float* __restrict__ b_anc,
    const float* __restrict__ b_cat,
    const float* __restrict__ W_out, const float* __restrict__ b_out,
    float* __restrict__ ws, float* __restrict__ out)
{
    __shared__ float hb[MB*H_];
    __shared__ float ancl[MB*52];
    __shared__ float hc[MB*H_];
    __shared__ float lg[MB*32];
    __shared__ float smx[MB], sinv[MB], ysum[MB];
    __shared__ float sq[MB*32];
    const int tid = threadIdx.x;
    const int bb0 = blockIdx.x * MB;

    for (int i = tid; i < MB*H_; i += 128) hb[i] = ws[WS_HFIN + (size_t)bb0*H_ + i];
    for (int i = tid; i < MB*E_; i += 128) {
        int b = i / E_, e = i - b*E_;
        float s = b_anc[e];
        #pragma unroll
        for (int a = 0; a < A_; ++a) s = fmaf(ancillary[(bb0+b)*A_ + a], W_anc[e*A_ + a], s);
        ancl[b*52+e] = fmaxf(s, 0.f);
    }
    __syncthreads();
    {
        const int j = tid;
        float s[MB];
        #pragma unroll
        for (int b = 0; b < MB; ++b) s[b] = b_cat[j];
        const float* wc = ws + WS_WCATT;
        for (int k = 0; k < H_; ++k) {
            float wv = wc[k*H_ + j];
            #pragma unroll
            for (int b = 0; b < MB; ++b) s[b] = fmaf(hb[b*H_+k], wv, s[b]);
        }
        for (int k = 0; k < E_; ++k) {
            float wv = wc[(H_+k)*H_ + j];
            #pragma unroll
            for (int b = 0; b < MB; ++b) s[b] = fmaf(ancl[b*52+k], wv, s[b]);
        }
        #pragma unroll
        for (int b = 0; b < MB; ++b) hc[b*H_+j] = fmaxf(s[b], 0.f);
    }
    __syncthreads();
    for (int i = tid; i < MB*O_; i += 128) {
        int b = i / O_, o = i - b*O_;
        float s = b_out[o];
        for (int k = 0; k < H_; ++k) s = fmaf(hc[b*H_+k], W_out[o*H_+k], s);
        lg[b*32+o] = s;
    }
    __syncthreads();
    if (tid < MB) {
        float mx = -1e30f;
        for (int o = 0; o < O_; ++o) mx = fmaxf(mx, lg[tid*32+o]);
        float se = 0.f;
        for (int o = 0; o < O_; ++o) se += __expf(lg[tid*32+o] - mx);
        smx[tid] = mx; sinv[tid] = 1.f / se;
    }
    __syncthreads();
    for (int i = tid; i < MB*O_; i += 128) {
        int b = i / O_, o = i - b*O_;
        float y = __expf(lg[b*32+o] - smx[b]) * sinv[b];
        out[OUT_YH + (size_t)(bb0+b)*O_ + o] = y;
        float d = y - probs[(size_t)(bb0+b)*O_ + o];
        sq[b*32+o] = d*d;
    }
    __syncthreads();
    if (tid < MB) {
        float s = 0.f;
        for (int o = 0; o < O_; ++o) s += sq[tid*32+o];
        ysum[tid] = s;
        out[OUT_LAB + bb0 + tid] = (float)labels[bb0 + tid];
    }
    __syncthreads();
    if (tid == 0) {
        float s = 0.f;
        #pragma unroll
        for (int b = 0; b < MB; ++b) s += ysum[b];
        atomicAdd(&ws[WS_ACC+1], s);
    }
}

// ================= finalize scalars =================
__global__ void rits_fin(const float* __restrict__ ws, float* __restrict__ out)
{
    if (blockIdx.x == 0 && threadIdx.x == 0) {
        float xl = ws[WS_ACC] * 0.3f;
        float yl = ws[WS_ACC+1] * (1.0f / (8192.0f + 1e-5f));
        out[0] = xl; out[1] = yl; out[2] = xl + yl;
    }
}

extern "C" void kernel_launch(void* const* d_in, const int* in_sizes, int n_in,
                              void* d_out, int out_size, void* d_ws, size_t ws_size,
                              hipStream_t stream)
{
    const float* values = (const float*)d_in[0];
    const float* masks  = (const float*)d_in[1];
    const float* deltas = (const float*)d_in[2];
    const float* probs  = (const float*)d_in[3];
    const float* ancil  = (const float*)d_in[4];
    const int*   labels = (const int*)  d_in[5];
    const float* W_td_h = (const float*)d_in[6];
    const float* b_td_h = (const float*)d_in[7];
    const float* W_td_x = (const float*)d_in[8];
    const float* b_td_x = (const float*)d_in[9];
    const float* W_hist = (const float*)d_in[10];
    const float* b_hist = (const float*)d_in[11];
    const float* W_feat = (const float*)d_in[12];
    const float* b_feat = (const float*)d_in[13];
    const float* W_comb = (const float*)d_in[14];
    const float* b_comb = (const float*)d_in[15];
    const float* W_ih   = (const float*)d_in[16];
    const float* W_hh   = (const float*)d_in[17];
    const float* b_ih   = (const float*)d_in[18];
    const float* b_hh   = (const float*)d_in[19];
    const float* W_anc  = (const float*)d_in[20];
    const float* b_anc  = (const float*)d_in[21];
    const float* W_cat  = (const float*)d_in[22];
    const float* b_cat  = (const float*)d_in[23];
    const float* W_out  = (const float*)d_in[24];
    const float* b_out  = (const float*)d_in[25];
    float* ws  = (float*)d_ws;
    float* out = (float*)d_out;

    hipLaunchKernelGGL(rits_prep, dim3((H_*178 + 255)/256), dim3(256), 0, stream, W_cat, ws);
    hipLaunchKernelGGL(rits_msum, dim3(7*MS_BG), dim3(256), 0, stream, masks, ws);
    hipLaunchKernelGGL(rits_main, dim3(B_/NB), dim3(NTHR), 0, stream,
                       values, masks, deltas, W_td_h, b_td_h, W_td_x, b_td_x,
                       W_hist, b_hist, W_feat, b_feat, W_comb, b_comb,
                       W_ih, W_hh, b_ih, b_hh, ws, out);
    hipLaunchKernelGGL(rits_head, dim3(B_/MB), dim3(128), 0, stream,
                       probs, ancil, labels, W_anc, b_anc, b_cat, W_out, b_out, ws, out);
    hipLaunchKernelGGL(rits_fin, dim3(1), dim3(1), 0, stream, ws, out);
}